// Round 13
// baseline (309.751 us; speedup 1.0000x reference)
//
#include <hip/hip_runtime.h>
#include <stdint.h>

#define B_    8
#define T_    769
#define C_    1024
#define H_    16
#define COND_ 256
#define NTOK  (B_*T_)     // 6152
#define BH_   (B_*H_)     // 128
#define TP_   896         // padded T for V^T rows

typedef short    v8s  __attribute__((ext_vector_type(8)));   // 8 bf16 (4 VGPRs)
typedef float    v4f  __attribute__((ext_vector_type(4)));   // 4 fp32 acc
typedef uint16_t u16x4 __attribute__((ext_vector_type(4)));
typedef uint16_t u16x8 __attribute__((ext_vector_type(8)));

__device__ __forceinline__ uint16_t f2bf(float f) {
  uint32_t u = __builtin_bit_cast(uint32_t, f);
  u += 0x7fffu + ((u >> 16) & 1u);          // RNE
  return (uint16_t)(u >> 16);
}
__device__ __forceinline__ float bf2f(uint16_t h) {
  uint32_t u = ((uint32_t)h) << 16;
  return __builtin_bit_cast(float, u);
}

// async global->LDS, 16B per lane. LDS dest must be wave-uniform base + lane*16.
__device__ __forceinline__ void gl_lds16(const void* gptr, void* lptr) {
  __builtin_amdgcn_global_load_lds(
      (const __attribute__((address_space(1))) uint32_t*)gptr,
      (__attribute__((address_space(3))) uint32_t*)lptr,
      16, 0, 0);
}

// T1: bijective XCD swizzle.
__device__ __forceinline__ int xcd_swz_bij(int orig, int nwg) {
  int q = nwg >> 3, r = nwg & 7;
  int xcd = orig & 7;
  int base = (xcd < r) ? xcd * (q + 1) : r * (q + 1) + (xcd - r) * q;
  return base + (orig >> 3);
}

// ---------------------------------------------------------------- convert f32->bf16
__global__ __launch_bounds__(256) void convert_bf16(
    const float* xq, const float* xkv, const float* wq, const float* wk,
    const float* wv, const float* wp,
    uint16_t* dxq, uint16_t* dxkv, uint16_t* dwq, uint16_t* dwk,
    uint16_t* dwv, uint16_t* dwp)
{
  int bid = blockIdx.x;
  const float* s; uint16_t* d; int base;
  if (bid < 6152)       { s = xq;  d = dxq;  base = bid; }
  else if (bid < 12304) { s = xkv; d = dxkv; base = bid - 6152; }
  else {
    int r = bid - 12304;
    int wsel = r >> 10; base = r & 1023;
    s = (wsel == 0) ? wq : (wsel == 1) ? wk : (wsel == 2) ? wv : wp;
    d = (wsel == 0) ? dwq : (wsel == 1) ? dwk : (wsel == 2) ? dwv : dwp;
  }
  int i = base * 256 + threadIdx.x;
  float4 f = ((const float4*)s)[i];
  u16x4 o;
  o[0] = f2bf(f.x); o[1] = f2bf(f.y); o[2] = f2bf(f.z); o[3] = f2bf(f.w);
  ((u16x4*)d)[i] = o;
}

// ================================================================ gemm_qkv
// R9-verified: 128x128 tile, BK=32, pair-packed conflict-free LDS (0 conflicts),
// dbuf counted vmcnt(4), 32 KB LDS -> 5 blocks/CU. 70.0 us. DO NOT TOUCH.
__global__ __launch_bounds__(256) void gemm_qkv(
    const uint16_t* xq, const uint16_t* xkv, const uint16_t* Wqkv,
    const float* bq, const float* bk, const float* bv, const float* freqs,
    uint16_t* Q, uint16_t* K, uint16_t* V)
{
  __shared__ uint16_t sA[2][4096];   // 128 rows x 32 k bf16 = 8 KB per buffer
  __shared__ uint16_t sB[2][4096];

  const int tid = threadIdx.x;
  const int lane = tid & 63, w = tid >> 6, quad = lane >> 4, l15 = lane & 15;
  const int rbase = (w >> 1) * 64, cbase = (w & 1) * 64;

  const int swz = xcd_swz_bij(blockIdx.x, 1176);
  const int ct = swz % 24, rt = swz / 24;
  const int z = ct >> 3;
  const int col0 = ct * 128, row0 = rt * 128;
  const uint16_t* A = (z == 0) ? xq : xkv;
  const float* bias  = (z == 0) ? bq : (z == 1 ? bk : bv);
  uint16_t* dst      = (z == 0) ? Q  : (z == 1 ? K  : V);

  const uint16_t* Ap[2];
  const uint16_t* Bp[2];
  #pragma unroll
  for (int r = 0; r < 2; r++) {
    int Cc = r * 256 + tid;
    int sr = Cc >> 3, sc = (Cc & 7) ^ (sr & 7);
    int row = sr * 2 + (sc >> 2), kc = sc & 3;
    Ap[r] = A    + (size_t)min(row0 + row, NTOK - 1) * 1024 + kc * 8;
    Bp[r] = Wqkv + (size_t)(col0 + row) * 1024 + kc * 8;
  }

  int offA[4], offB[4];
  #pragma unroll
  for (int i = 0; i < 4; i++) {
    int m = rbase + i * 16 + l15;
    int s0 = m >> 1;
    offA[i] = s0 * 64 + (((((m & 1) << 2) | quad) ^ (s0 & 7)) * 8);
    int n = cbase + i * 16 + l15;
    int sn = n >> 1;
    offB[i] = sn * 64 + (((((n & 1) << 2) | quad) ^ (sn & 7)) * 8);
  }

  v4f acc[4][4];
  #pragma unroll
  for (int i = 0; i < 4; i++)
    #pragma unroll
    for (int j = 0; j < 4; j++) acc[i][j] = (v4f)0.0f;

  #pragma unroll
  for (int r = 0; r < 2; r++) {
    gl_lds16(Ap[r] + 0,  sA[0] + (r * 256 + tid) * 8);
    gl_lds16(Bp[r] + 0,  sB[0] + (r * 256 + tid) * 8);
  }
  #pragma unroll
  for (int r = 0; r < 2; r++) {
    gl_lds16(Ap[r] + 32, sA[1] + (r * 256 + tid) * 8);
    gl_lds16(Bp[r] + 32, sB[1] + (r * 256 + tid) * 8);
  }

  #pragma unroll 1
  for (int t = 0; t < 32; t++) {
    if (t < 31) {
      asm volatile("s_waitcnt vmcnt(4)" ::: "memory");
    } else {
      asm volatile("s_waitcnt vmcnt(0)" ::: "memory");
    }
    __builtin_amdgcn_s_barrier();
    asm volatile("" ::: "memory");
    const uint16_t* cA = (t & 1) ? sA[1] : sA[0];
    const uint16_t* cB = (t & 1) ? sB[1] : sB[0];
    v8s af[4], bf[4];
    #pragma unroll
    for (int i = 0; i < 4; i++) af[i] = *(const v8s*)(cA + offA[i]);
    #pragma unroll
    for (int j = 0; j < 4; j++) bf[j] = *(const v8s*)(cB + offB[j]);
    asm volatile("s_waitcnt lgkmcnt(0)" ::: "memory");
    __builtin_amdgcn_s_barrier();
    asm volatile("" ::: "memory");
    if (t + 2 < 32) {
      uint16_t* nA = (t & 1) ? sA[1] : sA[0];
      uint16_t* nB = (t & 1) ? sB[1] : sB[0];
      int k0 = (t + 2) * 32;
      #pragma unroll
      for (int r = 0; r < 2; r++) {
        gl_lds16(Ap[r] + k0, nA + (r * 256 + tid) * 8);
        gl_lds16(Bp[r] + k0, nB + (r * 256 + tid) * 8);
      }
    }
    #pragma unroll
    for (int i = 0; i < 4; i++)
      #pragma unroll
      for (int j = 0; j < 4; j++)
        acc[i][j] = __builtin_amdgcn_mfma_f32_16x16x32_bf16(af[i], bf[j], acc[i][j], 0, 0, 0);
  }

  #pragma unroll
  for (int i = 0; i < 4; i++) {
    #pragma unroll
    for (int reg = 0; reg < 4; reg++) {
      int n = row0 + rbase + i * 16 + quad * 4 + reg;
      bool ok = (n < NTOK);
      int nn = min(n, NTOK - 1);
      int b = nn / T_, t = nn % T_;
      float vj[4];
      #pragma unroll
      for (int j = 0; j < 4; j++)
        vj[j] = acc[i][j][reg] + bias[(col0 + cbase + j * 16 + l15) & 1023];
      if (z < 2) {
        float v0 = vj[0], v1 = vj[1];
        float p0 = __shfl_xor(v0, 1);
        float p1 = __shfl_xor(v1, 1);
        float f0 = freqs[t * 32 + l15];
        float f1 = freqs[t * 32 + 16 + l15];
        float s0, c0, s1, c1;
        __sincosf(f0, &s0, &c0);
        __sincosf(f1, &s1, &c1);
        if (l15 & 1) { vj[0] = v0 * c0 + p0 * s0; vj[1] = v1 * c1 + p1 * s1; }
        else         { vj[0] = v0 * c0 - p0 * s0; vj[1] = v1 * c1 - p1 * s1; }
      }
      if (z == 0) {
        #pragma unroll
        for (int j = 0; j < 4; j++) vj[j] *= 0.125f;
      }
      if (ok) {
        #pragma unroll
        for (int j = 0; j < 4; j++) {
          int col = col0 + cbase + j * 16 + l15;
          int h = (col >> 6) & 15, d = col & 63;
          dst[((size_t)(b * H_ + h) * T_ + t) * 64 + d] = f2bf(vj[j]);
        }
      }
    }
  }
}

// ---------------------------------------------------------------- 128x128 GEMM
// (gemm_out) — BK=64 2-phase dbuf, counted vmcnt (exact R9 build, measured
// inside the 267.1 total).
__device__ __forceinline__ void gemm_stage64(
    const uint16_t* const Aptr[4], const uint16_t* const Bptr[4],
    int k0, uint16_t* sA, uint16_t* sB, int tid)
{
  #pragma unroll
  for (int r = 0; r < 4; r++) {
    gl_lds16(Aptr[r] + k0, sA + (r * 256 + tid) * 8);
    gl_lds16(Bptr[r] + k0, sB + (r * 256 + tid) * 8);
  }
}

__device__ __forceinline__ void gemm_compute64(
    const uint16_t* sAc, const uint16_t* sBc, v4f acc[4][4],
    int rbase, int cbase, int quad, int l15)
{
  #pragma unroll
  for (int s = 0; s < 2; s++) {
    v8s af[4], bfv[4];
    #pragma unroll
    for (int i = 0; i < 4; i++) {
      int m = rbase + i * 16 + l15;
      af[i] = *(const v8s*)(sAc + m * 64 + (((s * 4 + quad) ^ (m & 7)) * 8));
    }
    #pragma unroll
    for (int j = 0; j < 4; j++) {
      int n = cbase + j * 16 + l15;
      bfv[j] = *(const v8s*)(sBc + n * 64 + (((s * 4 + quad) ^ (n & 7)) * 8));
    }
    #pragma unroll
    for (int i = 0; i < 4; i++)
      #pragma unroll
      for (int j = 0; j < 4; j++)
        acc[i][j] = __builtin_amdgcn_mfma_f32_16x16x32_bf16(af[i], bfv[j], acc[i][j], 0, 0, 0);
  }
}

__device__ __forceinline__ void gemm_mainloop64(
    const uint16_t* A, const uint16_t* W, int M, int row0, int col0,
    v4f acc[4][4], uint16_t* sA, uint16_t* sB)   // sA,sB each 2*128*64
{
  const int tid = threadIdx.x;
  const int lane = tid & 63, w = tid >> 6, quad = lane >> 4, l15 = lane & 15;
  const int rbase = (w >> 1) * 64, cbase = (w & 1) * 64;

  const uint16_t* Aptr[4];
  const uint16_t* Bptr[4];
  #pragma unroll
  for (int r = 0; r < 4; r++) {
    int c = r * 256 + tid;
    int row = c >> 3, qp = c & 7;
    int g = qp ^ (row & 7);
    Aptr[r] = A + (size_t)min(row0 + row, M - 1) * 1024 + g * 8;
    Bptr[r] = W + (size_t)(col0 + row) * 1024 + g * 8;
  }

  #pragma unroll
  for (int i = 0; i < 4; i++)
    #pragma unroll
    for (int j = 0; j < 4; j++) acc[i][j] = (v4f)0.0f;

  uint16_t* sA0 = sA;         uint16_t* sB0 = sB;
  uint16_t* sA1 = sA + 8192;  uint16_t* sB1 = sB + 8192;

  gemm_stage64(Aptr, Bptr, 0,  sA0, sB0, tid);
  gemm_stage64(Aptr, Bptr, 64, sA1, sB1, tid);

  #pragma unroll 1
  for (int t = 0; t < 16; t++) {
    if (t < 15) {
      asm volatile("s_waitcnt vmcnt(8)" ::: "memory");
    } else {
      asm volatile("s_waitcnt vmcnt(0)" ::: "memory");
    }
    __builtin_amdgcn_s_barrier();
    asm volatile("" ::: "memory");
    uint16_t* cA = (t & 1) ? sA1 : sA0;
    uint16_t* cB = (t & 1) ? sB1 : sB0;
    gemm_compute64(cA, cB, acc, rbase, cbase, quad, l15);
    asm volatile("s_waitcnt lgkmcnt(0)" ::: "memory");
    __builtin_amdgcn_s_barrier();
    asm volatile("" ::: "memory");
    if (t + 2 < 16)
      gemm_stage64(Aptr, Bptr, (t + 2) * 64, cA, cB, tid);
  }
}

// Output projection: f32 -> d_out [NTOK][1024]. Grid: 392 blocks 1D, XCD-swizzled.
__global__ __launch_bounds__(256) void gemm_out(
    const uint16_t* Y, const uint16_t* wp, const float* bp, float* out)
{
  __shared__ uint16_t sA[2 * 128 * 64];
  __shared__ uint16_t sB[2 * 128 * 64];
  const int swz = xcd_swz_bij(blockIdx.x, 392);
  const int ct = swz & 7, rt = swz >> 3;
  const int col0 = ct * 128, row0 = rt * 128;
  v4f acc[4][4];
  gemm_mainloop64(Y, wp, NTOK, row0, col0, acc, sA, sB);

  const int tid = threadIdx.x;
  const int lane = tid & 63, w = tid >> 6, quad = lane >> 4, l15 = lane & 15;
  const int rbase = (w >> 1) * 64, cbase = (w & 1) * 64;
  #pragma unroll
  for (int i = 0; i < 4; i++) {
    #pragma unroll
    for (int reg = 0; reg < 4; reg++) {
      int n = row0 + rbase + i * 16 + quad * 4 + reg;
      if (n < NTOK) {
        #pragma unroll
        for (int j = 0; j < 4; j++) {
          int col = col0 + cbase + j * 16 + l15;
          out[(size_t)n * 1024 + col] = acc[i][j][reg] + bp[col];
        }
      }
    }
  }
}

// ---------------------------------------------------------------- V transpose
__global__ __launch_bounds__(256) void transpose_v(const uint16_t* Vb, uint16_t* Vt)
{
  __shared__ uint16_t sT[64 * 64];
  const int tid = threadIdx.x;
  const int t0 = blockIdx.x * 64, bh = blockIdx.y;
  const uint16_t* src = Vb + (size_t)bh * T_ * 64;
  #pragma unroll
  for (int r = 0; r < 2; r++) {
    int task = r * 256 + tid;
    int t = task >> 3, oc = task & 7;
    int gt = min(t0 + t, T_ - 1);
    u16x8 v = *(const u16x8*)(src + (size_t)gt * 64 + oc * 8);
    int p = oc ^ (t & 7) ^ ((t >> 3) & 7);
    *(u16x8*)(sT + t * 64 + p * 8) = v;
  }
  __syncthreads();
  uint16_t* dst = Vt + (size_t)bh * 64 * TP_;
  #pragma unroll
  for (int r = 0; r < 2; r++) {
    int task = r * 256 + tid;
    int o = task & 7, d = task >> 3;
    u16x8 v;
    #pragma unroll
    for (int k = 0; k < 8; k++) {
      int t = o * 8 + k;
      int p = (d >> 3) ^ k ^ o;
      v[k] = sT[t * 64 + p * 8 + (d & 7)];
    }
    *(u16x8*)(dst + (size_t)d * TP_ + t0 + o * 8) = v;
  }
}

// ---------------------------------------------------------------- flash attention
// R3's proven structure (q64, 4 waves, 1664 blocks), ONE change: V^T is read
// DIRECTLY from global (L2-resident: each bh's V^T panel is ~200 KB shared by
// 13 XCD-local q-blocks) instead of being staged to sVT. LDS 50.2 -> 33.8 KB
// -> 4 blocks/CU (16 waves, vs 12) and half the per-ktile staging/drain work.
// Un-swizzled global chunk for PV fragment (ks,quad): Vtb + d*TP_ + k0 +
// (ks*4+quad)*8  [verified: stage map (p&8)|((p^d)&7) composed with read map
// (c8^(d&7)) yields logical chunk c8 = ks*4+quad].
__global__ __launch_bounds__(256) void attn(
    const uint16_t* Q, const uint16_t* K, const uint16_t* Vt, uint16_t* Y)
{
  __shared__ uint16_t sK[128 * 64];
  __shared__ uint16_t sP[4 * 16 * 136];

  const int tid = threadIdx.x;
  const int lane = tid & 63, w = tid >> 6, quad = lane >> 4, l15 = lane & 15;
  const int swz = xcd_swz_bij(blockIdx.x, 1664);
  const int qt = swz % 13, bh = swz / 13;
  const int b = bh >> 4, h = bh & 15;
  const int q0 = qt * 64;

  const uint16_t* Qb = Q + (size_t)bh * T_ * 64;
  const uint16_t* Kb = K + (size_t)bh * T_ * 64;
  const uint16_t* Vtb = Vt + (size_t)bh * 64 * TP_;

  const int qr = min(q0 + w * 16 + l15, T_ - 1);
  v8s aq0 = *(const v8s*)(Qb + (size_t)qr * 64 + quad * 8);
  v8s aq1 = *(const v8s*)(Qb + (size_t)qr * 64 + 32 + quad * 8);

  float l_r[4] = {0.f, 0.f, 0.f, 0.f};
  v4f o[4];
  #pragma unroll
  for (int r = 0; r < 4; r++) o[r] = (v4f)0.0f;

  const int kend = min(T_, q0 + 319);       // max col = 255 + (q0+63)
  const int nkt = (kend + 127) >> 7;

  for (int kt = 0; kt < nkt; kt++) {
    const int k0 = kt * 128;
    // stage K tile only (natural layout, XOR-8 swizzle)
    #pragma unroll
    for (int r = 0; r < 4; r++) {
      int c = r * 256 + tid;
      int key = c >> 3, qp = c & 7;
      int g = qp ^ (key & 7);
      int gk = min(k0 + key, T_ - 1);
      gl_lds16(Kb + (size_t)gk * 64 + g * 8, sK + c * 8);
    }
    __syncthreads();

    v4f s[8];
    #pragma unroll
    for (int cb = 0; cb < 8; cb++) {
      int key_l = cb * 16 + l15;
      v8s b0 = *(const v8s*)(sK + (key_l * 8 + ((quad) ^ (key_l & 7))) * 8);
      v8s b1 = *(const v8s*)(sK + (key_l * 8 + ((4 + quad) ^ (key_l & 7))) * 8);
      v4f zz = (v4f)0.0f;
      zz = __builtin_amdgcn_mfma_f32_16x16x32_bf16(aq0, b0, zz, 0, 0, 0);
      zz = __builtin_amdgcn_mfma_f32_16x16x32_bf16(aq1, b1, zz, 0, 0, 0);
      s[cb] = zz;
    }

    uint16_t* pw = sP + w * (16 * 136);
    const int qrow_base = q0 + w * 16 + quad * 4;
    const bool full = (k0 + 128 <= COND_ + q0) && (k0 + 128 <= T_);
    if (full) {
      #pragma unroll
      for (int reg = 0; reg < 4; reg++) {
        float rs = 0.f;
        #pragma unroll
        for (int cb = 0; cb < 8; cb++) {
          float pv = __expf(s[cb][reg]);
          uint16_t pb = f2bf(pv);
          rs += bf2f(pb);
          pw[(quad * 4 + reg) * 136 + cb * 16 + l15] = pb;
        }
        #pragma unroll
        for (int off = 1; off < 16; off <<= 1) rs += __shfl_xor(rs, off);
        l_r[reg] += rs;
      }
    } else {
      #pragma unroll
      for (int reg = 0; reg < 4; reg++) {
        int lim = min(COND_ + qrow_base + reg, T_);
        float rs = 0.f;
        #pragma unroll
        for (int cb = 0; cb < 8; cb++) {
          int key = k0 + cb * 16 + l15;
          float pv = (key < lim) ? __expf(s[cb][reg]) : 0.f;
          uint16_t pb = f2bf(pv);
          rs += bf2f(pb);
          pw[(quad * 4 + reg) * 136 + cb * 16 + l15] = pb;
        }
        #pragma unroll
        for (int off = 1; off < 16; off <<= 1) rs += __shfl_xor(rs, off);
        l_r[reg] += rs;
      }
    }

    // O += P V : V^T fragments straight from global (L2-hot)
    #pragma unroll
    for (int ks = 0; ks < 4; ks++) {
      v8s ap = *(const v8s*)(pw + l15 * 136 + ks * 32 + quad * 8);
      #pragma unroll
      for (int cbd = 0; cbd < 4; cbd++) {
        int d = cbd * 16 + l15;
        v8s bv = *(const v8s*)(Vtb + (size_t)d * TP_ + k0 + (ks * 4 + quad) * 8);
        o[cbd] = __builtin_amdgcn_mfma_f32_16x16x32_bf16(ap, bv, o[cbd], 0, 0, 0);
      }
    }
    __syncthreads();   // all waves done with sK (and sP) before restage
  }

  #pragma unroll
  for (int reg = 0; reg < 4; reg++) {
    int t = q0 + w * 16 + quad * 4 + reg;
    if (t < T_) {
      float inv = 1.0f / l_r[reg];
      #pragma unroll
      for (int cbd = 0; cbd < 4; cbd++) {
        int d = cbd * 16 + l15;
        Y[((size_t)(b * T_ + t)) * C_ + h * 64 + d] = f2bf(o[cbd][reg] * inv);
      }
    }
  }
}

// ---------------------------------------------------------------- launch
extern "C" void kernel_launch(void* const* d_in, const int* in_sizes, int n_in,
                              void* d_out, int out_size, void* d_ws, size_t ws_size,
                              hipStream_t stream)
{
  const float* x_q   = (const float*)d_in[0];
  const float* x_kv  = (const float*)d_in[1];
  const float* freqs = (const float*)d_in[2];
  const float* Wq = (const float*)d_in[3];
  const float* bq = (const float*)d_in[4];
  const float* Wk = (const float*)d_in[5];
  const float* bk = (const float*)d_in[6];
  const float* Wv = (const float*)d_in[7];
  const float* bv = (const float*)d_in[8];
  const float* Wp = (const float*)d_in[9];
  const float* bp = (const float*)d_in[10];
  float* out = (float*)d_out;

  const size_t SZX = (size_t)NTOK * C_;     // 6,299,648
  const size_t SZW = (size_t)C_ * C_;       // 1,048,576
  uint16_t* ws = (uint16_t*)d_ws;
  uint16_t* xq_bf  = ws;
  uint16_t* xkv_bf = xq_bf + SZX;
  uint16_t* wq_bf  = xkv_bf + SZX;   // wq/wk/wv contiguous = packed Wqkv[3072][1024]
  uint16_t* wk_bf  = wq_bf + SZW;
  uint16_t* wv_bf  = wk_bf + SZW;
  uint16_t* wp_bf  = wv_bf + SZW;
  uint16_t* Qb = wp_bf + SZW;
  uint16_t* Kb = Qb + SZX;
  uint16_t* Vb = Kb + SZX;
  uint16_t* Vt = ws;                 // over dead xq/xkv
  uint16_t* Yb = Vb;                 // attn output over dead natural-V

  convert_bf16<<<dim3(16400), 256, 0, stream>>>(
      x_q, x_kv, Wq, Wk, Wv, Wp, xq_bf, xkv_bf, wq_bf, wk_bf, wv_bf, wp_bf);

  gemm_qkv<<<dim3(1176), 256, 0, stream>>>(
      xq_bf, xkv_bf, wq_bf, bq, bk, bv, freqs, Qb, Kb, Vb);

  transpose_v<<<dim3(13, BH_), 256, 0, stream>>>(Vb, Vt);

  attn<<<dim3(1664), 256, 0, stream>>>(Qb, Kb, Vt, Yb);

  gemm_out<<<dim3(392), 256, 0, stream>>>(Yb, wp_bf, bp, out);
}

// Round 14
// 266.975 us; speedup vs baseline: 1.1602x; 1.1602x over previous
//
#include <hip/hip_runtime.h>
#include <stdint.h>

#define B_    8
#define T_    769
#define C_    1024
#define H_    16
#define COND_ 256
#define NTOK  (B_*T_)     // 6152
#define BH_   (B_*H_)     // 128
#define TP_   896         // padded T for V^T rows

typedef short    v8s  __attribute__((ext_vector_type(8)));   // 8 bf16 (4 VGPRs)
typedef float    v4f  __attribute__((ext_vector_type(4)));   // 4 fp32 acc
typedef uint16_t u16x4 __attribute__((ext_vector_type(4)));
typedef uint16_t u16x8 __attribute__((ext_vector_type(8)));

__device__ __forceinline__ uint16_t f2bf(float f) {
  uint32_t u = __builtin_bit_cast(uint32_t, f);
  u += 0x7fffu + ((u >> 16) & 1u);          // RNE
  return (uint16_t)(u >> 16);
}
__device__ __forceinline__ float bf2f(uint16_t h) {
  uint32_t u = ((uint32_t)h) << 16;
  return __builtin_bit_cast(float, u);
}

// async global->LDS, 16B per lane. LDS dest must be wave-uniform base + lane*16.
__device__ __forceinline__ void gl_lds16(const void* gptr, void* lptr) {
  __builtin_amdgcn_global_load_lds(
      (const __attribute__((address_space(1))) uint32_t*)gptr,
      (__attribute__((address_space(3))) uint32_t*)lptr,
      16, 0, 0);
}

// T1: bijective XCD swizzle.
__device__ __forceinline__ int xcd_swz_bij(int orig, int nwg) {
  int q = nwg >> 3, r = nwg & 7;
  int xcd = orig & 7;
  int base = (xcd < r) ? xcd * (q + 1) : r * (q + 1) + (xcd - r) * q;
  return base + (orig >> 3);
}

// ---------------------------------------------------------------- convert f32->bf16
__global__ __launch_bounds__(256) void convert_bf16(
    const float* xq, const float* xkv, const float* wq, const float* wk,
    const float* wv, const float* wp,
    uint16_t* dxq, uint16_t* dxkv, uint16_t* dwq, uint16_t* dwk,
    uint16_t* dwv, uint16_t* dwp)
{
  int bid = blockIdx.x;
  const float* s; uint16_t* d; int base;
  if (bid < 6152)       { s = xq;  d = dxq;  base = bid; }
  else if (bid < 12304) { s = xkv; d = dxkv; base = bid - 6152; }
  else {
    int r = bid - 12304;
    int wsel = r >> 10; base = r & 1023;
    s = (wsel == 0) ? wq : (wsel == 1) ? wk : (wsel == 2) ? wv : wp;
    d = (wsel == 0) ? dwq : (wsel == 1) ? dwk : (wsel == 2) ? dwv : dwp;
  }
  int i = base * 256 + threadIdx.x;
  float4 f = ((const float4*)s)[i];
  u16x4 o;
  o[0] = f2bf(f.x); o[1] = f2bf(f.y); o[2] = f2bf(f.z); o[3] = f2bf(f.w);
  ((u16x4*)d)[i] = o;
}

// ================================================================ gemm_qkv
// R9-verified: 128x128 tile, BK=32, pair-packed conflict-free LDS (0 conflicts),
// dbuf counted vmcnt(4), 32 KB LDS -> 5 blocks/CU. 70.0 us. Final form.
__global__ __launch_bounds__(256) void gemm_qkv(
    const uint16_t* xq, const uint16_t* xkv, const uint16_t* Wqkv,
    const float* bq, const float* bk, const float* bv, const float* freqs,
    uint16_t* Q, uint16_t* K, uint16_t* V)
{
  __shared__ uint16_t sA[2][4096];   // 128 rows x 32 k bf16 = 8 KB per buffer
  __shared__ uint16_t sB[2][4096];

  const int tid = threadIdx.x;
  const int lane = tid & 63, w = tid >> 6, quad = lane >> 4, l15 = lane & 15;
  const int rbase = (w >> 1) * 64, cbase = (w & 1) * 64;

  const int swz = xcd_swz_bij(blockIdx.x, 1176);
  const int ct = swz % 24, rt = swz / 24;
  const int z = ct >> 3;
  const int col0 = ct * 128, row0 = rt * 128;
  const uint16_t* A = (z == 0) ? xq : xkv;
  const float* bias  = (z == 0) ? bq : (z == 1 ? bk : bv);
  uint16_t* dst      = (z == 0) ? Q  : (z == 1 ? K  : V);

  const uint16_t* Ap[2];
  const uint16_t* Bp[2];
  #pragma unroll
  for (int r = 0; r < 2; r++) {
    int Cc = r * 256 + tid;
    int sr = Cc >> 3, sc = (Cc & 7) ^ (sr & 7);
    int row = sr * 2 + (sc >> 2), kc = sc & 3;
    Ap[r] = A    + (size_t)min(row0 + row, NTOK - 1) * 1024 + kc * 8;
    Bp[r] = Wqkv + (size_t)(col0 + row) * 1024 + kc * 8;
  }

  int offA[4], offB[4];
  #pragma unroll
  for (int i = 0; i < 4; i++) {
    int m = rbase + i * 16 + l15;
    int s0 = m >> 1;
    offA[i] = s0 * 64 + (((((m & 1) << 2) | quad) ^ (s0 & 7)) * 8);
    int n = cbase + i * 16 + l15;
    int sn = n >> 1;
    offB[i] = sn * 64 + (((((n & 1) << 2) | quad) ^ (sn & 7)) * 8);
  }

  v4f acc[4][4];
  #pragma unroll
  for (int i = 0; i < 4; i++)
    #pragma unroll
    for (int j = 0; j < 4; j++) acc[i][j] = (v4f)0.0f;

  #pragma unroll
  for (int r = 0; r < 2; r++) {
    gl_lds16(Ap[r] + 0,  sA[0] + (r * 256 + tid) * 8);
    gl_lds16(Bp[r] + 0,  sB[0] + (r * 256 + tid) * 8);
  }
  #pragma unroll
  for (int r = 0; r < 2; r++) {
    gl_lds16(Ap[r] + 32, sA[1] + (r * 256 + tid) * 8);
    gl_lds16(Bp[r] + 32, sB[1] + (r * 256 + tid) * 8);
  }

  #pragma unroll 1
  for (int t = 0; t < 32; t++) {
    if (t < 31) {
      asm volatile("s_waitcnt vmcnt(4)" ::: "memory");
    } else {
      asm volatile("s_waitcnt vmcnt(0)" ::: "memory");
    }
    __builtin_amdgcn_s_barrier();
    asm volatile("" ::: "memory");
    const uint16_t* cA = (t & 1) ? sA[1] : sA[0];
    const uint16_t* cB = (t & 1) ? sB[1] : sB[0];
    v8s af[4], bf[4];
    #pragma unroll
    for (int i = 0; i < 4; i++) af[i] = *(const v8s*)(cA + offA[i]);
    #pragma unroll
    for (int j = 0; j < 4; j++) bf[j] = *(const v8s*)(cB + offB[j]);
    asm volatile("s_waitcnt lgkmcnt(0)" ::: "memory");
    __builtin_amdgcn_s_barrier();
    asm volatile("" ::: "memory");
    if (t + 2 < 32) {
      uint16_t* nA = (t & 1) ? sA[1] : sA[0];
      uint16_t* nB = (t & 1) ? sB[1] : sB[0];
      int k0 = (t + 2) * 32;
      #pragma unroll
      for (int r = 0; r < 2; r++) {
        gl_lds16(Ap[r] + k0, nA + (r * 256 + tid) * 8);
        gl_lds16(Bp[r] + k0, nB + (r * 256 + tid) * 8);
      }
    }
    #pragma unroll
    for (int i = 0; i < 4; i++)
      #pragma unroll
      for (int j = 0; j < 4; j++)
        acc[i][j] = __builtin_amdgcn_mfma_f32_16x16x32_bf16(af[i], bf[j], acc[i][j], 0, 0, 0);
  }

  #pragma unroll
  for (int i = 0; i < 4; i++) {
    #pragma unroll
    for (int reg = 0; reg < 4; reg++) {
      int n = row0 + rbase + i * 16 + quad * 4 + reg;
      bool ok = (n < NTOK);
      int nn = min(n, NTOK - 1);
      int b = nn / T_, t = nn % T_;
      float vj[4];
      #pragma unroll
      for (int j = 0; j < 4; j++)
        vj[j] = acc[i][j][reg] + bias[(col0 + cbase + j * 16 + l15) & 1023];
      if (z < 2) {
        float v0 = vj[0], v1 = vj[1];
        float p0 = __shfl_xor(v0, 1);
        float p1 = __shfl_xor(v1, 1);
        float f0 = freqs[t * 32 + l15];
        float f1 = freqs[t * 32 + 16 + l15];
        float s0, c0, s1, c1;
        __sincosf(f0, &s0, &c0);
        __sincosf(f1, &s1, &c1);
        if (l15 & 1) { vj[0] = v0 * c0 + p0 * s0; vj[1] = v1 * c1 + p1 * s1; }
        else         { vj[0] = v0 * c0 - p0 * s0; vj[1] = v1 * c1 - p1 * s1; }
      }
      if (z == 0) {
        #pragma unroll
        for (int j = 0; j < 4; j++) vj[j] *= 0.125f;
      }
      if (ok) {
        #pragma unroll
        for (int j = 0; j < 4; j++) {
          int col = col0 + cbase + j * 16 + l15;
          int h = (col >> 6) & 15, d = col & 63;
          dst[((size_t)(b * H_ + h) * T_ + t) * 64 + d] = f2bf(vj[j]);
        }
      }
    }
  }
}

// ---------------------------------------------------------------- 128x128 GEMM
// (gemm_out) — BK=64 2-phase dbuf, counted vmcnt (exact R9 build).
__device__ __forceinline__ void gemm_stage64(
    const uint16_t* const Aptr[4], const uint16_t* const Bptr[4],
    int k0, uint16_t* sA, uint16_t* sB, int tid)
{
  #pragma unroll
  for (int r = 0; r < 4; r++) {
    gl_lds16(Aptr[r] + k0, sA + (r * 256 + tid) * 8);
    gl_lds16(Bptr[r] + k0, sB + (r * 256 + tid) * 8);
  }
}

__device__ __forceinline__ void gemm_compute64(
    const uint16_t* sAc, const uint16_t* sBc, v4f acc[4][4],
    int rbase, int cbase, int quad, int l15)
{
  #pragma unroll
  for (int s = 0; s < 2; s++) {
    v8s af[4], bfv[4];
    #pragma unroll
    for (int i = 0; i < 4; i++) {
      int m = rbase + i * 16 + l15;
      af[i] = *(const v8s*)(sAc + m * 64 + (((s * 4 + quad) ^ (m & 7)) * 8));
    }
    #pragma unroll
    for (int j = 0; j < 4; j++) {
      int n = cbase + j * 16 + l15;
      bfv[j] = *(const v8s*)(sBc + n * 64 + (((s * 4 + quad) ^ (n & 7)) * 8));
    }
    #pragma unroll
    for (int i = 0; i < 4; i++)
      #pragma unroll
      for (int j = 0; j < 4; j++)
        acc[i][j] = __builtin_amdgcn_mfma_f32_16x16x32_bf16(af[i], bfv[j], acc[i][j], 0, 0, 0);
  }
}

__device__ __forceinline__ void gemm_mainloop64(
    const uint16_t* A, const uint16_t* W, int M, int row0, int col0,
    v4f acc[4][4], uint16_t* sA, uint16_t* sB)   // sA,sB each 2*128*64
{
  const int tid = threadIdx.x;
  const int lane = tid & 63, w = tid >> 6, quad = lane >> 4, l15 = lane & 15;
  const int rbase = (w >> 1) * 64, cbase = (w & 1) * 64;

  const uint16_t* Aptr[4];
  const uint16_t* Bptr[4];
  #pragma unroll
  for (int r = 0; r < 4; r++) {
    int c = r * 256 + tid;
    int row = c >> 3, qp = c & 7;
    int g = qp ^ (row & 7);
    Aptr[r] = A + (size_t)min(row0 + row, M - 1) * 1024 + g * 8;
    Bptr[r] = W + (size_t)(col0 + row) * 1024 + g * 8;
  }

  #pragma unroll
  for (int i = 0; i < 4; i++)
    #pragma unroll
    for (int j = 0; j < 4; j++) acc[i][j] = (v4f)0.0f;

  uint16_t* sA0 = sA;         uint16_t* sB0 = sB;
  uint16_t* sA1 = sA + 8192;  uint16_t* sB1 = sB + 8192;

  gemm_stage64(Aptr, Bptr, 0,  sA0, sB0, tid);
  gemm_stage64(Aptr, Bptr, 64, sA1, sB1, tid);

  #pragma unroll 1
  for (int t = 0; t < 16; t++) {
    if (t < 15) {
      asm volatile("s_waitcnt vmcnt(8)" ::: "memory");
    } else {
      asm volatile("s_waitcnt vmcnt(0)" ::: "memory");
    }
    __builtin_amdgcn_s_barrier();
    asm volatile("" ::: "memory");
    uint16_t* cA = (t & 1) ? sA1 : sA0;
    uint16_t* cB = (t & 1) ? sB1 : sB0;
    gemm_compute64(cA, cB, acc, rbase, cbase, quad, l15);
    asm volatile("s_waitcnt lgkmcnt(0)" ::: "memory");
    __builtin_amdgcn_s_barrier();
    asm volatile("" ::: "memory");
    if (t + 2 < 16)
      gemm_stage64(Aptr, Bptr, (t + 2) * 64, cA, cB, tid);
  }
}

// Output projection: f32 -> d_out [NTOK][1024]. Grid: 392 blocks 1D, XCD-swizzled.
__global__ __launch_bounds__(256) void gemm_out(
    const uint16_t* Y, const uint16_t* wp, const float* bp, float* out)
{
  __shared__ uint16_t sA[2 * 128 * 64];
  __shared__ uint16_t sB[2 * 128 * 64];
  const int swz = xcd_swz_bij(blockIdx.x, 392);
  const int ct = swz & 7, rt = swz >> 3;
  const int col0 = ct * 128, row0 = rt * 128;
  v4f acc[4][4];
  gemm_mainloop64(Y, wp, NTOK, row0, col0, acc, sA, sB);

  const int tid = threadIdx.x;
  const int lane = tid & 63, w = tid >> 6, quad = lane >> 4, l15 = lane & 15;
  const int rbase = (w >> 1) * 64, cbase = (w & 1) * 64;
  #pragma unroll
  for (int i = 0; i < 4; i++) {
    #pragma unroll
    for (int reg = 0; reg < 4; reg++) {
      int n = row0 + rbase + i * 16 + quad * 4 + reg;
      if (n < NTOK) {
        #pragma unroll
        for (int j = 0; j < 4; j++) {
          int col = col0 + cbase + j * 16 + l15;
          out[(size_t)n * 1024 + col] = acc[i][j][reg] + bp[col];
        }
      }
    }
  }
}

// ---------------------------------------------------------------- V transpose
__global__ __launch_bounds__(256) void transpose_v(const uint16_t* Vb, uint16_t* Vt)
{
  __shared__ uint16_t sT[64 * 64];
  const int tid = threadIdx.x;
  const int t0 = blockIdx.x * 64, bh = blockIdx.y;
  const uint16_t* src = Vb + (size_t)bh * T_ * 64;
  #pragma unroll
  for (int r = 0; r < 2; r++) {
    int task = r * 256 + tid;
    int t = task >> 3, oc = task & 7;
    int gt = min(t0 + t, T_ - 1);
    u16x8 v = *(const u16x8*)(src + (size_t)gt * 64 + oc * 8);
    int p = oc ^ (t & 7) ^ ((t >> 3) & 7);
    *(u16x8*)(sT + t * 64 + p * 8) = v;
  }
  __syncthreads();
  uint16_t* dst = Vt + (size_t)bh * 64 * TP_;
  #pragma unroll
  for (int r = 0; r < 2; r++) {
    int task = r * 256 + tid;
    int o = task & 7, d = task >> 3;
    u16x8 v;
    #pragma unroll
    for (int k = 0; k < 8; k++) {
      int t = o * 8 + k;
      int p = (d >> 3) ^ k ^ o;
      v[k] = sT[t * 64 + p * 8 + (d & 7)];
    }
    *(u16x8*)(dst + (size_t)d * TP_ + t0 + o * 8) = v;
  }
}

// ---------------------------------------------------------------- flash attention
// R3/R9 proven form: 4 waves x 16 q-rows; 128-key tiles; sK + sVT both
// gl_lds16-staged (XOR-8 swizzle); fixed-max softmax via wave-private sP.
// R13 proved the staging is load-bearing: direct-global V^T puts 16 L2-latency
// loads on the MFMA critical path per ktile (attn 65 -> 105 us).
__global__ __launch_bounds__(256) void attn(
    const uint16_t* Q, const uint16_t* K, const uint16_t* Vt, uint16_t* Y)
{
  __shared__ uint16_t sK[128 * 64];
  __shared__ uint16_t sVT[64 * 128];
  __shared__ uint16_t sP[4 * 16 * 136];

  const int tid = threadIdx.x;
  const int lane = tid & 63, w = tid >> 6, quad = lane >> 4, l15 = lane & 15;
  const int swz = xcd_swz_bij(blockIdx.x, 1664);
  const int qt = swz % 13, bh = swz / 13;
  const int b = bh >> 4, h = bh & 15;
  const int q0 = qt * 64;

  const uint16_t* Qb = Q + (size_t)bh * T_ * 64;
  const uint16_t* Kb = K + (size_t)bh * T_ * 64;
  const uint16_t* Vtb = Vt + (size_t)bh * 64 * TP_;

  const int qr = min(q0 + w * 16 + l15, T_ - 1);
  v8s aq0 = *(const v8s*)(Qb + (size_t)qr * 64 + quad * 8);
  v8s aq1 = *(const v8s*)(Qb + (size_t)qr * 64 + 32 + quad * 8);

  float l_r[4] = {0.f, 0.f, 0.f, 0.f};
  v4f o[4];
  #pragma unroll
  for (int r = 0; r < 4; r++) o[r] = (v4f)0.0f;

  const int kend = min(T_, q0 + 319);       // max col = 255 + (q0+63)
  const int nkt = (kend + 127) >> 7;

  for (int kt = 0; kt < nkt; kt++) {
    const int k0 = kt * 128;
    #pragma unroll
    for (int r = 0; r < 4; r++) {
      int c = r * 256 + tid;
      int key = c >> 3, qp = c & 7;
      int g = qp ^ (key & 7);
      int gk = min(k0 + key, T_ - 1);
      gl_lds16(Kb + (size_t)gk * 64 + g * 8, sK + c * 8);
    }
    #pragma unroll
    for (int r = 0; r < 4; r++) {
      int c = r * 256 + tid;
      int d = c >> 4, p = c & 15;
      int g = (p & 8) | ((p ^ d) & 7);
      gl_lds16(Vtb + (size_t)d * TP_ + k0 + g * 8, sVT + c * 8);
    }
    __syncthreads();

    v4f s[8];
    #pragma unroll
    for (int cb = 0; cb < 8; cb++) {
      int key_l = cb * 16 + l15;
      v8s b0 = *(const v8s*)(sK + (key_l * 8 + ((quad) ^ (key_l & 7))) * 8);
      v8s b1 = *(const v8s*)(sK + (key_l * 8 + ((4 + quad) ^ (key_l & 7))) * 8);
      v4f zz = (v4f)0.0f;
      zz = __builtin_amdgcn_mfma_f32_16x16x32_bf16(aq0, b0, zz, 0, 0, 0);
      zz = __builtin_amdgcn_mfma_f32_16x16x32_bf16(aq1, b1, zz, 0, 0, 0);
      s[cb] = zz;
    }

    uint16_t* pw = sP + w * (16 * 136);
    const int qrow_base = q0 + w * 16 + quad * 4;
    const bool full = (k0 + 128 <= COND_ + q0) && (k0 + 128 <= T_);
    if (full) {
      #pragma unroll
      for (int reg = 0; reg < 4; reg++) {
        float rs = 0.f;
        #pragma unroll
        for (int cb = 0; cb < 8; cb++) {
          float pv = __expf(s[cb][reg]);
          uint16_t pb = f2bf(pv);
          rs += bf2f(pb);
          pw[(quad * 4 + reg) * 136 + cb * 16 + l15] = pb;
        }
        #pragma unroll
        for (int off = 1; off < 16; off <<= 1) rs += __shfl_xor(rs, off);
        l_r[reg] += rs;
      }
    } else {
      #pragma unroll
      for (int reg = 0; reg < 4; reg++) {
        int lim = min(COND_ + qrow_base + reg, T_);
        float rs = 0.f;
        #pragma unroll
        for (int cb = 0; cb < 8; cb++) {
          int key = k0 + cb * 16 + l15;
          float pv = (key < lim) ? __expf(s[cb][reg]) : 0.f;
          uint16_t pb = f2bf(pv);
          rs += bf2f(pb);
          pw[(quad * 4 + reg) * 136 + cb * 16 + l15] = pb;
        }
        #pragma unroll
        for (int off = 1; off < 16; off <<= 1) rs += __shfl_xor(rs, off);
        l_r[reg] += rs;
      }
    }

    #pragma unroll
    for (int ks = 0; ks < 4; ks++) {
      v8s ap = *(const v8s*)(pw + l15 * 136 + ks * 32 + quad * 8);
      #pragma unroll
      for (int cbd = 0; cbd < 4; cbd++) {
        int d = cbd * 16 + l15;
        v8s bv = *(const v8s*)(sVT + d * 128 + (((ks * 4 + quad) ^ (d & 7)) * 8));
        o[cbd] = __builtin_amdgcn_mfma_f32_16x16x32_bf16(ap, bv, o[cbd], 0, 0, 0);
      }
    }
    __syncthreads();
  }

  #pragma unroll
  for (int reg = 0; reg < 4; reg++) {
    int t = q0 + w * 16 + quad * 4 + reg;
    if (t < T_) {
      float inv = 1.0f / l_r[reg];
      #pragma unroll
      for (int cbd = 0; cbd < 4; cbd++) {
        int d = cbd * 16 + l15;
        Y[((size_t)(b * T_ + t)) * C_ + h * 64 + d] = f2bf(o[cbd][reg] * inv);
      }
    }
  }
}

// ---------------------------------------------------------------- launch
extern "C" void kernel_launch(void* const* d_in, const int* in_sizes, int n_in,
                              void* d_out, int out_size, void* d_ws, size_t ws_size,
                              hipStream_t stream)
{
  const float* x_q   = (const float*)d_in[0];
  const float* x_kv  = (const float*)d_in[1];
  const float* freqs = (const float*)d_in[2];
  const float* Wq = (const float*)d_in[3];
  const float* bq = (const float*)d_in[4];
  const float* Wk = (const float*)d_in[5];
  const float* bk = (const float*)d_in[6];
  const float* Wv = (const float*)d_in[7];
  const float* bv = (const float*)d_in[8];
  const float* Wp = (const float*)d_in[9];
  const float* bp = (const float*)d_in[10];
  float* out = (float*)d_out;

  const size_t SZX = (size_t)NTOK * C_;     // 6,299,648
  const size_t SZW = (size_t)C_ * C_;       // 1,048,576
  uint16_t* ws = (uint16_t*)d_ws;
  uint16_t* xq_bf  = ws;
  uint16_t* xkv_bf = xq_bf + SZX;
  uint16_t* wq_bf  = xkv_bf + SZX;   // wq/wk/wv contiguous = packed Wqkv[3072][1024]
  uint16_t* wk_bf  = wq_bf + SZW;
  uint16_t* wv_bf  = wk_bf + SZW;
  uint16_t* wp_bf  = wv_bf + SZW;
  uint16_t* Qb = wp_bf + SZW;
  uint16_t* Kb = Qb + SZX;
  uint16_t* Vb = Kb + SZX;
  uint16_t* Vt = ws;                 // over dead xq/xkv
  uint16_t* Yb = Vb;                 // attn output over dead natural-V

  convert_bf16<<<dim3(16400), 256, 0, stream>>>(
      x_q, x_kv, Wq, Wk, Wv, Wp, xq_bf, xkv_bf, wq_bf, wk_bf, wv_bf, wp_bf);

  gemm_qkv<<<dim3(1176), 256, 0, stream>>>(
      xq_bf, xkv_bf, wq_bf, bq, bk, bv, freqs, Qb, Kb, Vb);

  transpose_v<<<dim3(13, BH_), 256, 0, stream>>>(Vb, Vt);

  attn<<<dim3(1664), 256, 0, stream>>>(Qb, Kb, Vt, Yb);

  gemm_out<<<dim3(392), 256, 0, stream>>>(Yb, wp_bf, bp, out);
}